// Round 1
// baseline (5698.143 us; speedup 1.0000x reference)
//
#include <hip/hip_runtime.h>
#include <hip/hip_bf16.h>
#include <math.h>

// Problem constants
#define S_ENS 10
#define B_DIM 256
#define SD 16
#define OD 8
#define H_DIM 3200
#define OUT1 512
#define IN_DIM 48
#define M_ROWS (S_ENS * B_DIM)     // 2560
#define TEMP_INV 10.0f

__device__ __forceinline__ float sigmoidf_(float x) { return 1.0f / (1.0f + expf(-x)); }

// ---------------------------------------------------------------------------
// Kernel 1: system-model prep.  One block, 256 threads (thread = batch idx).
// x_predicted = tanh(x_fp @ F^T); residual = y_t - x_pred @ H^T;
// inp = concat[delta_x_prev, residual, x_fp - x_fpp, y_prev]
// ---------------------------------------------------------------------------
__global__ void prep_k(const float* __restrict__ y_t, const float* __restrict__ xfp,
                       const float* __restrict__ xfpp, const float* __restrict__ yprev,
                       const float* __restrict__ dxp, const float* __restrict__ Fm,
                       const float* __restrict__ Hm,
                       float* __restrict__ xpred, float* __restrict__ resid,
                       float* __restrict__ inp) {
    int b = threadIdx.x;
    float xrow[SD], xp[SD];
    for (int k = 0; k < SD; ++k) xrow[k] = xfp[b * SD + k];
    for (int s = 0; s < SD; ++s) {
        float acc = 0.f;
        for (int k = 0; k < SD; ++k) acc += xrow[k] * Fm[s * SD + k];
        xp[s] = tanhf(acc);
        xpred[b * SD + s] = xp[s];
    }
    float res[OD];
    for (int o = 0; o < OD; ++o) {
        float acc = 0.f;
        for (int s = 0; s < SD; ++s) acc += xp[s] * Hm[o * SD + s];
        res[o] = y_t[b * OD + o] - acc;
        resid[b * OD + o] = res[o];
    }
    float* ir = inp + b * IN_DIM;
    for (int k = 0; k < SD; ++k) ir[k] = dxp[b * SD + k];
    for (int o = 0; o < OD; ++o) ir[SD + o] = res[o];
    for (int k = 0; k < SD; ++k) ir[SD + OD + k] = xrow[k] - xfpp[b * SD + k];
    for (int o = 0; o < OD; ++o) ir[SD + OD + SD + o] = yprev[b * OD + o];
}

// ---------------------------------------------------------------------------
// Kernel 2: a = relu(inp @ fc_in_w^T + b).  Block per batch row.
// ---------------------------------------------------------------------------
__global__ void fc_in_k(const float* __restrict__ inp, const float* __restrict__ w,
                        const float* __restrict__ bias, float* __restrict__ a) {
    int b = blockIdx.x;
    __shared__ float row[IN_DIM];
    int t = threadIdx.x;
    if (t < IN_DIM) row[t] = inp[b * IN_DIM + t];
    __syncthreads();
    for (int j = t; j < H_DIM; j += 256) {
        float s = bias[j];
        const float* wr = w + j * IN_DIM;
        #pragma unroll 8
        for (int k = 0; k < IN_DIM; ++k) s += row[k] * wr[k];
        a[b * H_DIM + j] = fmaxf(s, 0.f);
    }
}

// ---------------------------------------------------------------------------
// Kernel 3: X[i,b,j] = concrete_dropout(a[b,j], u1[i,b,j], p1)
// grid = (B*H/256, S)
// ---------------------------------------------------------------------------
__global__ void dropx_k(const float* __restrict__ a, const float* __restrict__ u1,
                        const float* __restrict__ pl1, float* __restrict__ X) {
    int idx_in = blockIdx.x * 256 + threadIdx.x;          // 0 .. B*H-1
    int i = blockIdx.y;
    float p = sigmoidf_(pl1[0]);
    float lp = logf(p) - log1pf(-p);
    float inv = 1.0f / (1.0f - p);
    int gidx = i * (B_DIM * H_DIM) + idx_in;
    float u = u1[gidx];
    float z = sigmoidf_((lp + logf(u) - log1pf(-u)) * TEMP_INV);
    X[gidx] = a[idx_in] * (1.0f - z) * inv;
}

// ---------------------------------------------------------------------------
// Kernel 4: fused GRU.  C = GRU(X, Hprev) over rows M=2560, cols N=3200, K=3200.
// 64x64 block tile, BK=16, 256 threads, 4x4 micro-tile, 6 accumulator sets
// (r/z/n gates from W_ih and W_hh).  Epilogue applies gate nonlinearity.
// ---------------------------------------------------------------------------
__global__ __launch_bounds__(256) void gru_fused_k(
    const float* __restrict__ X, const float* __restrict__ Hprev,
    const float* __restrict__ W_ih, const float* __restrict__ W_hh,
    const float* __restrict__ b_ih, const float* __restrict__ b_hh,
    float* __restrict__ Hnew) {
    __shared__ __align__(16) float AsX[16 * 64];
    __shared__ __align__(16) float AsH[16 * 64];
    __shared__ __align__(16) float Bs[6][16 * 64];

    int tid = threadIdx.x;
    int bm = blockIdx.y, bn = blockIdx.x;
    int tx = tid & 15, ty = tid >> 4;
    int lrow = tid >> 2;            // 0..63 : row within tile for loading
    int kq = (tid & 3) * 4;         // 0,4,8,12 : k-offset for float4 load

    float acc[6][4][4] = {};

    const float* xg = X + (bm * 64 + lrow) * H_DIM + kq;
    const float* hg = Hprev + (bm * 64 + lrow) * H_DIM + kq;
    const float* wg[6];
    #pragma unroll
    for (int g = 0; g < 3; ++g) {
        wg[g]     = W_ih + (size_t)(g * H_DIM + bn * 64 + lrow) * H_DIM + kq;
        wg[3 + g] = W_hh + (size_t)(g * H_DIM + bn * 64 + lrow) * H_DIM + kq;
    }

    for (int k0 = 0; k0 < H_DIM; k0 += 16) {
        float4 vx = *(const float4*)(xg + k0);
        float4 vh = *(const float4*)(hg + k0);
        float4 vw[6];
        #pragma unroll
        for (int g = 0; g < 6; ++g) vw[g] = *(const float4*)(wg[g] + k0);
        __syncthreads();
        AsX[(kq + 0) * 64 + lrow] = vx.x; AsX[(kq + 1) * 64 + lrow] = vx.y;
        AsX[(kq + 2) * 64 + lrow] = vx.z; AsX[(kq + 3) * 64 + lrow] = vx.w;
        AsH[(kq + 0) * 64 + lrow] = vh.x; AsH[(kq + 1) * 64 + lrow] = vh.y;
        AsH[(kq + 2) * 64 + lrow] = vh.z; AsH[(kq + 3) * 64 + lrow] = vh.w;
        #pragma unroll
        for (int g = 0; g < 6; ++g) {
            Bs[g][(kq + 0) * 64 + lrow] = vw[g].x; Bs[g][(kq + 1) * 64 + lrow] = vw[g].y;
            Bs[g][(kq + 2) * 64 + lrow] = vw[g].z; Bs[g][(kq + 3) * 64 + lrow] = vw[g].w;
        }
        __syncthreads();
        #pragma unroll
        for (int k = 0; k < 16; ++k) {
            float ax[4], ah[4], bv[6][4];
            *(float4*)ax = *(const float4*)&AsX[k * 64 + ty * 4];
            *(float4*)ah = *(const float4*)&AsH[k * 64 + ty * 4];
            #pragma unroll
            for (int g = 0; g < 6; ++g)
                *(float4*)bv[g] = *(const float4*)&Bs[g][k * 64 + tx * 4];
            #pragma unroll
            for (int g = 0; g < 6; ++g) {
                #pragma unroll
                for (int mi = 0; mi < 4; ++mi) {
                    float av = (g < 3) ? ax[mi] : ah[mi];
                    #pragma unroll
                    for (int ni = 0; ni < 4; ++ni)
                        acc[g][mi][ni] = fmaf(av, bv[g][ni], acc[g][mi][ni]);
                }
            }
        }
    }

    int row0 = bm * 64 + ty * 4;
    int col0 = bn * 64 + tx * 4;
    #pragma unroll
    for (int mi = 0; mi < 4; ++mi) {
        int r_ = row0 + mi;
        #pragma unroll
        for (int ni = 0; ni < 4; ++ni) {
            int c = col0 + ni;
            float gxr = acc[0][mi][ni] + b_ih[c];
            float ghr = acc[3][mi][ni] + b_hh[c];
            float gxz = acc[1][mi][ni] + b_ih[H_DIM + c];
            float ghz = acc[4][mi][ni] + b_hh[H_DIM + c];
            float gxn = acc[2][mi][ni] + b_ih[2 * H_DIM + c];
            float ghn = acc[5][mi][ni] + b_hh[2 * H_DIM + c];
            float r = sigmoidf_(gxr + ghr);
            float z = sigmoidf_(gxz + ghz);
            float n = tanhf(gxn + r * ghn);
            float hold = Hprev[r_ * H_DIM + c];
            Hnew[r_ * H_DIM + c] = (1.0f - z) * n + z * hold;
        }
    }
}

// ---------------------------------------------------------------------------
// Kernel 5: o = concrete_dropout(relu(Hnew @ fc1_w^T + fc1_b), u2, p2)
// M=2560, N=512, K=3200 tiled GEMM, same tile scheme, one accumulator set.
// ---------------------------------------------------------------------------
__global__ __launch_bounds__(256) void fc1_fused_k(
    const float* __restrict__ Hn, const float* __restrict__ W,
    const float* __restrict__ bias, const float* __restrict__ u2,
    const float* __restrict__ pl2, float* __restrict__ O) {
    __shared__ __align__(16) float As[16 * 64];
    __shared__ __align__(16) float Bs[16 * 64];
    int tid = threadIdx.x;
    int bm = blockIdx.y, bn = blockIdx.x;
    int tx = tid & 15, ty = tid >> 4;
    int lrow = tid >> 2;
    int kq = (tid & 3) * 4;
    float acc[4][4] = {};
    const float* ag = Hn + (bm * 64 + lrow) * H_DIM + kq;
    const float* wg = W + (bn * 64 + lrow) * H_DIM + kq;
    for (int k0 = 0; k0 < H_DIM; k0 += 16) {
        float4 va = *(const float4*)(ag + k0);
        float4 vb = *(const float4*)(wg + k0);
        __syncthreads();
        As[(kq + 0) * 64 + lrow] = va.x; As[(kq + 1) * 64 + lrow] = va.y;
        As[(kq + 2) * 64 + lrow] = va.z; As[(kq + 3) * 64 + lrow] = va.w;
        Bs[(kq + 0) * 64 + lrow] = vb.x; Bs[(kq + 1) * 64 + lrow] = vb.y;
        Bs[(kq + 2) * 64 + lrow] = vb.z; Bs[(kq + 3) * 64 + lrow] = vb.w;
        __syncthreads();
        #pragma unroll
        for (int k = 0; k < 16; ++k) {
            float a4[4], b4[4];
            *(float4*)a4 = *(const float4*)&As[k * 64 + ty * 4];
            *(float4*)b4 = *(const float4*)&Bs[k * 64 + tx * 4];
            #pragma unroll
            for (int mi = 0; mi < 4; ++mi)
                #pragma unroll
                for (int ni = 0; ni < 4; ++ni)
                    acc[mi][ni] = fmaf(a4[mi], b4[ni], acc[mi][ni]);
        }
    }
    float p = sigmoidf_(pl2[0]);
    float lp = logf(p) - log1pf(-p);
    float inv = 1.0f / (1.0f - p);
    int row0 = bm * 64 + ty * 4;
    int col0 = bn * 64 + tx * 4;
    #pragma unroll
    for (int mi = 0; mi < 4; ++mi) {
        int r_ = row0 + mi;
        #pragma unroll
        for (int ni = 0; ni < 4; ++ni) {
            int c = col0 + ni;
            float v = fmaxf(acc[mi][ni] + bias[c], 0.f);
            float u = u2[r_ * OUT1 + c];
            float z = sigmoidf_((lp + logf(u) - log1pf(-u)) * TEMP_INV);
            O[r_ * OUT1 + c] = v * (1.0f - z) * inv;
        }
    }
}

// ---------------------------------------------------------------------------
// Kernel 6: K = o @ fc2_w^T + fc2_b, xf = x_pred + K @ residual.
// Block per (i,b) row, 128 threads: thread = (s, o) pair; reduce over o.
// ---------------------------------------------------------------------------
__global__ void fc2_corr_k(const float* __restrict__ O, const float* __restrict__ w,
                           const float* __restrict__ bias, const float* __restrict__ resid,
                           const float* __restrict__ xpred, float* __restrict__ xf_ens) {
    int row = blockIdx.x;            // i*B + b
    int b = row & (B_DIM - 1);
    __shared__ __align__(16) float orow[OUT1];
    int t = threadIdx.x;
    for (int k = t; k < OUT1; k += 128) orow[k] = O[row * OUT1 + k];
    __syncthreads();
    int s = t >> 3, oo = t & 7;
    const float* wr = w + (s * OD + oo) * OUT1;
    float sum = 0.f;
    for (int k = 0; k < OUT1; k += 4) {
        float4 ov = *(const float4*)&orow[k];
        float4 wv = *(const float4*)&wr[k];
        sum += ov.x * wv.x + ov.y * wv.y + ov.z * wv.z + ov.w * wv.w;
    }
    sum += bias[s * OD + oo];
    float v = sum * resid[b * OD + oo];
    v += __shfl_down(v, 4, 8);
    v += __shfl_down(v, 2, 8);
    v += __shfl_down(v, 1, 8);
    if (oo == 0) xf_ens[row * SD + s] = xpred[b * SD + s] + v;
}

// ---------------------------------------------------------------------------
// Kernel 7: ensemble mean + covariance.  Block per batch row.
// out[0:4096] = x_filtered_final; out[4096:69632] = P.
// ---------------------------------------------------------------------------
__global__ void stats_k(const float* __restrict__ xf_ens, float* __restrict__ out) {
    int b = blockIdx.x;
    __shared__ float xf[S_ENS][SD];
    __shared__ float mean[SD];
    int t = threadIdx.x;
    if (t < S_ENS * SD) {
        int s = t >> 4, k = t & 15;
        xf[s][k] = xf_ens[s * (B_DIM * SD) + b * SD + k];
    }
    __syncthreads();
    if (t < SD) {
        float m = 0.f;
        for (int s = 0; s < S_ENS; ++s) m += xf[s][t];
        m *= (1.0f / S_ENS);
        mean[t] = m;
        out[b * SD + t] = m;
    }
    __syncthreads();
    int i = t >> 4, j = t & 15;
    float p = 0.f;
    for (int s = 0; s < S_ENS; ++s) p += (xf[s][i] - mean[i]) * (xf[s][j] - mean[j]);
    out[B_DIM * SD + b * 256 + t] = p * (1.0f / S_ENS);
}

// ---------------------------------------------------------------------------
// Kernel 8: sum of squares reduction (grid-stride, atomic per block).
// ---------------------------------------------------------------------------
__global__ void sumsq_k(const float* __restrict__ w, int n, float* __restrict__ accum) {
    float s = 0.f;
    for (int i = blockIdx.x * blockDim.x + threadIdx.x; i < n; i += gridDim.x * blockDim.x) {
        float v = w[i];
        s += v * v;
    }
    #pragma unroll
    for (int d = 32; d >= 1; d >>= 1) s += __shfl_down(s, d, 64);
    __shared__ float red[4];
    int lane = threadIdx.x & 63, wv = threadIdx.x >> 6;
    if (lane == 0) red[wv] = s;
    __syncthreads();
    if (threadIdx.x == 0) atomicAdd(accum, red[0] + red[1] + red[2] + red[3]);
}

// ---------------------------------------------------------------------------
// Kernel 9: regularizer -> out[69632 .. 69641]
// ---------------------------------------------------------------------------
__global__ void write_reg_k(const float* __restrict__ sums, const float* __restrict__ pl1,
                            const float* __restrict__ pl2, float* __restrict__ out) {
    int t = threadIdx.x;
    float p1 = sigmoidf_(pl1[0]);
    float p2 = sigmoidf_(pl2[0]);
    float ent1 = p1 * logf(p1) + (1.f - p1) * log1pf(-p1);
    float ent2 = p2 * logf(p2) + (1.f - p2) * log1pf(-p2);
    float reg = sums[0] / (1.f - p1) + (float)H_DIM * ent1
              + sums[1] / (1.f - p2) + (float)OUT1 * ent2;
    if (t < S_ENS) out[B_DIM * SD + B_DIM * SD * SD + t] = reg;
}

// ---------------------------------------------------------------------------
extern "C" void kernel_launch(void* const* d_in, const int* in_sizes, int n_in,
                              void* d_out, int out_size, void* d_ws, size_t ws_size,
                              hipStream_t stream) {
    const float* y_t     = (const float*)d_in[0];
    const float* xfp     = (const float*)d_in[1];
    const float* xfpp    = (const float*)d_in[2];
    const float* yprev   = (const float*)d_in[3];
    const float* dxp     = (const float*)d_in[4];
    const float* hprev   = (const float*)d_in[5];
    const float* Fm      = (const float*)d_in[6];
    const float* Hm      = (const float*)d_in[7];
    const float* fc_in_w = (const float*)d_in[8];
    const float* fc_in_b = (const float*)d_in[9];
    const float* W_ih    = (const float*)d_in[10];
    const float* W_hh    = (const float*)d_in[11];
    const float* b_ih    = (const float*)d_in[12];
    const float* b_hh    = (const float*)d_in[13];
    const float* fc1_w   = (const float*)d_in[14];
    const float* fc1_b   = (const float*)d_in[15];
    const float* fc2_w   = (const float*)d_in[16];
    const float* fc2_b   = (const float*)d_in[17];
    const float* pl1     = (const float*)d_in[18];
    const float* pl2     = (const float*)d_in[19];
    const float* u1      = (const float*)d_in[20];
    const float* u2      = (const float*)d_in[21];
    float* out = (float*)d_out;
    float* ws  = (float*)d_ws;

    // workspace layout (float offsets)
    const size_t OFF_A     = 0;                                  // B*H      = 819200
    const size_t OFF_X     = OFF_A + (size_t)B_DIM * H_DIM;      // S*B*H    = 8192000
    const size_t OFF_HN    = OFF_X + (size_t)M_ROWS * H_DIM;     // S*B*H
    const size_t OFF_O     = OFF_HN + (size_t)M_ROWS * H_DIM;    // S*B*OUT1 = 1310720
    const size_t OFF_XF    = OFF_O + (size_t)M_ROWS * OUT1;      // S*B*SD   = 40960
    const size_t OFF_XPRED = OFF_XF + (size_t)M_ROWS * SD;       // B*SD
    const size_t OFF_RES   = OFF_XPRED + (size_t)B_DIM * SD;     // B*OD
    const size_t OFF_INP   = OFF_RES + (size_t)B_DIM * OD;       // B*IN
    const size_t OFF_SUMS  = OFF_INP + (size_t)B_DIM * IN_DIM;   // 2 floats

    float* a_buf   = ws + OFF_A;
    float* X_buf   = ws + OFF_X;
    float* Hn_buf  = ws + OFF_HN;
    float* O_buf   = ws + OFF_O;
    float* xf_buf  = ws + OFF_XF;
    float* xpred_b = ws + OFF_XPRED;
    float* res_b   = ws + OFF_RES;
    float* inp_b   = ws + OFF_INP;
    float* sums_b  = ws + OFF_SUMS;

    hipMemsetAsync(sums_b, 0, 2 * sizeof(float), stream);

    prep_k<<<1, 256, 0, stream>>>(y_t, xfp, xfpp, yprev, dxp, Fm, Hm,
                                  xpred_b, res_b, inp_b);
    fc_in_k<<<B_DIM, 256, 0, stream>>>(inp_b, fc_in_w, fc_in_b, a_buf);
    dropx_k<<<dim3(B_DIM * H_DIM / 256, S_ENS), 256, 0, stream>>>(a_buf, u1, pl1, X_buf);
    gru_fused_k<<<dim3(H_DIM / 64, M_ROWS / 64), 256, 0, stream>>>(
        X_buf, hprev, W_ih, W_hh, b_ih, b_hh, Hn_buf);
    fc1_fused_k<<<dim3(OUT1 / 64, M_ROWS / 64), 256, 0, stream>>>(
        Hn_buf, fc1_w, fc1_b, u2, pl2, O_buf);
    fc2_corr_k<<<M_ROWS, 128, 0, stream>>>(O_buf, fc2_w, fc2_b, res_b, xpred_b, xf_buf);
    stats_k<<<B_DIM, 256, 0, stream>>>(xf_buf, out);
    sumsq_k<<<256, 256, 0, stream>>>(fc_in_w, H_DIM * IN_DIM, sums_b);
    sumsq_k<<<1024, 256, 0, stream>>>(fc1_w, OUT1 * H_DIM, sums_b + 1);
    write_reg_k<<<1, 64, 0, stream>>>(sums_b, pl1, pl2, out);
}

// Round 2
// 1182.281 us; speedup vs baseline: 4.8196x; 4.8196x over previous
//
#include <hip/hip_runtime.h>
#include <hip/hip_bf16.h>
#include <math.h>

// Problem constants
#define S_ENS 10
#define B_DIM 256
#define SD 16
#define OD 8
#define H_DIM 3200
#define OUT1 512
#define IN_DIM 48
#define M_ROWS (S_ENS * B_DIM)     // 2560
#define TEMP_INV 10.0f

typedef unsigned short u16;
typedef __attribute__((ext_vector_type(8))) short short8;
typedef __attribute__((ext_vector_type(4))) float floatx4;

__device__ __forceinline__ float sigmoidf_(float x) { return 1.0f / (1.0f + __expf(-x)); }

// fp32 -> bf16 round-to-nearest-even
__device__ __forceinline__ u16 f2bf(float f) {
    union { float f; unsigned u; } v; v.f = f;
    unsigned u = v.u + 0x7fffu + ((v.u >> 16) & 1u);
    return (u16)(u >> 16);
}
__device__ __forceinline__ float bf2f(u16 h) {
    union { unsigned u; float f; } v; v.u = ((unsigned)h) << 16;
    return v.f;
}

// async global->LDS, 16B per lane. LDS dest: wave-uniform base + lane*16.
__device__ __forceinline__ void gld_lds16(const u16* g, u16* l) {
    __builtin_amdgcn_global_load_lds((const __attribute__((address_space(1))) void*)g,
                                     (__attribute__((address_space(3))) void*)l, 16, 0, 0);
}

// ---------------------------------------------------------------------------
// 128x128-tile bf16 MFMA K-loop (BK=32). A:(M,K) row-major bf16, B:(N,K)
// row-major bf16 (i.e. W as stored). LDS tiles 128 rows x 32 cols, 64B/row,
// 16B chunks XOR-swizzled by ((row>>1)&3) so frag ds_read_b128 is uniform
// across banks (2-way residual = free, m136).
// ---------------------------------------------------------------------------
__device__ __forceinline__ void kloop128(const u16* __restrict__ A, const u16* __restrict__ B,
                                         int m_base, int n_base, int kiters,
                                         u16* sA, u16* sB, floatx4 (&acc)[4][4]) {
    const int tid = threadIdx.x;
    const int wave = tid >> 6, lane = tid & 63;
    const int r = tid >> 2, c = tid & 3;
    const int swe = (c ^ ((r >> 1) & 3)) << 3;     // swizzled chunk offset (elements)
    const u16* Ag = A + (size_t)(m_base + r) * H_DIM + swe;
    const u16* Bg = B + (size_t)(n_base + r) * H_DIM + swe;
    u16* sA0 = sA + wave * 512;                    // per-wave 1KB staging base
    u16* sB0 = sB + wave * 512;
    const int frow = lane & 15, fch = lane >> 4;
    const int wrow0 = (wave >> 1) * 64, wcol0 = (wave & 1) * 64;
    int aoff[4], boff[4];
    #pragma unroll
    for (int mi = 0; mi < 4; ++mi) {
        int row = wrow0 + mi * 16 + frow;
        aoff[mi] = row * 32 + ((fch ^ ((row >> 1) & 3)) << 3);
    }
    #pragma unroll
    for (int ni = 0; ni < 4; ++ni) {
        int row = wcol0 + ni * 16 + frow;
        boff[ni] = row * 32 + ((fch ^ ((row >> 1) & 3)) << 3);
    }
    for (int kk = 0; kk < kiters; ++kk) {
        const u16* ga = Ag + kk * 32;
        const u16* gb = Bg + kk * 32;
        __syncthreads();
        gld_lds16(ga, sA0);
        gld_lds16(ga + (size_t)64 * H_DIM, sA0 + 2048);
        gld_lds16(gb, sB0);
        gld_lds16(gb + (size_t)64 * H_DIM, sB0 + 2048);
        __syncthreads();
        short8 af[4], bfr[4];
        #pragma unroll
        for (int mi = 0; mi < 4; ++mi) af[mi] = *(const short8*)(sA + aoff[mi]);
        #pragma unroll
        for (int ni = 0; ni < 4; ++ni) bfr[ni] = *(const short8*)(sB + boff[ni]);
        #pragma unroll
        for (int mi = 0; mi < 4; ++mi)
            #pragma unroll
            for (int ni = 0; ni < 4; ++ni)
                acc[mi][ni] = __builtin_amdgcn_mfma_f32_16x16x32_bf16(af[mi], bfr[ni], acc[mi][ni], 0, 0, 0);
    }
}

// ---------------------------------------------------------------------------
// Phase A: raw gate pre-activation GEMMs.
// z=0: R = X@Wih_r^T + Hp@Whh_r^T ; z=1: Z likewise ; z=2: GHN = Hp@Whh_n^T
// Output raw bf16 (biases applied in phase B).
// ---------------------------------------------------------------------------
__global__ __launch_bounds__(256) void gru_gemm_a(
    const u16* __restrict__ Xbf, const u16* __restrict__ Hpbf,
    const u16* __restrict__ Wih, const u16* __restrict__ Whh,
    u16* __restrict__ Rb, u16* __restrict__ Zb, u16* __restrict__ Gb) {
    __shared__ u16 sA[4096], sB[4096];
    floatx4 acc[4][4];
    #pragma unroll
    for (int i = 0; i < 4; ++i)
        #pragma unroll
        for (int j = 0; j < 4; ++j) acc[i][j] = (floatx4){0.f, 0.f, 0.f, 0.f};
    const int g = blockIdx.z;
    const int m_base = blockIdx.y * 128;
    const int nb = blockIdx.x * 128;
    const size_t gstride = (size_t)H_DIM * H_DIM;  // 3200 rows per gate slice
    u16* outp;
    if (g == 0) {
        kloop128(Xbf, Wih, m_base, nb, 100, sA, sB, acc);
        kloop128(Hpbf, Whh, m_base, nb, 100, sA, sB, acc);
        outp = Rb;
    } else if (g == 1) {
        kloop128(Xbf, Wih + gstride, m_base, nb, 100, sA, sB, acc);
        kloop128(Hpbf, Whh + gstride, m_base, nb, 100, sA, sB, acc);
        outp = Zb;
    } else {
        kloop128(Hpbf, Whh + 2 * gstride, m_base, nb, 100, sA, sB, acc);
        outp = Gb;
    }
    const int lane = threadIdx.x & 63, wave = threadIdx.x >> 6;
    const int wrow0 = (wave >> 1) * 64, wcol0 = (wave & 1) * 64;
    const int quad = lane >> 4, cc = lane & 15;
    #pragma unroll
    for (int mi = 0; mi < 4; ++mi) {
        #pragma unroll
        for (int ni = 0; ni < 4; ++ni) {
            int col = nb + wcol0 + ni * 16 + cc;
            int rw = m_base + wrow0 + mi * 16 + quad * 4;
            #pragma unroll
            for (int j = 0; j < 4; ++j)
                outp[(size_t)(rw + j) * H_DIM + col] = f2bf(acc[mi][ni][j]);
        }
    }
}

// ---------------------------------------------------------------------------
// Phase B: GXN GEMM + full GRU epilogue -> Hn (bf16).
// ---------------------------------------------------------------------------
__global__ __launch_bounds__(256) void gru_gemm_b(
    const u16* __restrict__ Xbf, const u16* __restrict__ Wih,
    const u16* __restrict__ Rb, const u16* __restrict__ Zb, const u16* __restrict__ Gb,
    const float* __restrict__ b_ih, const float* __restrict__ b_hh,
    const float* __restrict__ hprev, u16* __restrict__ Hn) {
    __shared__ u16 sA[4096], sB[4096];
    floatx4 acc[4][4];
    #pragma unroll
    for (int i = 0; i < 4; ++i)
        #pragma unroll
        for (int j = 0; j < 4; ++j) acc[i][j] = (floatx4){0.f, 0.f, 0.f, 0.f};
    const int m_base = blockIdx.y * 128;
    const int nb = blockIdx.x * 128;
    kloop128(Xbf, Wih + (size_t)2 * H_DIM * H_DIM, m_base, nb, 100, sA, sB, acc);
    const int lane = threadIdx.x & 63, wave = threadIdx.x >> 6;
    const int wrow0 = (wave >> 1) * 64, wcol0 = (wave & 1) * 64;
    const int quad = lane >> 4, cc = lane & 15;
    #pragma unroll
    for (int ni = 0; ni < 4; ++ni) {
        int col = nb + wcol0 + ni * 16 + cc;
        float bir = b_ih[col],            bhr = b_hh[col];
        float biz = b_ih[H_DIM + col],    bhz = b_hh[H_DIM + col];
        float bin_ = b_ih[2 * H_DIM + col], bhn = b_hh[2 * H_DIM + col];
        #pragma unroll
        for (int mi = 0; mi < 4; ++mi) {
            int rw = m_base + wrow0 + mi * 16 + quad * 4;
            #pragma unroll
            for (int j = 0; j < 4; ++j) {
                size_t idx = (size_t)(rw + j) * H_DIM + col;
                float rg = sigmoidf_(bf2f(Rb[idx]) + bir + bhr);
                float zg = sigmoidf_(bf2f(Zb[idx]) + biz + bhz);
                float ng = tanhf(acc[mi][ni][j] + bin_ + rg * (bf2f(Gb[idx]) + bhn));
                float h = hprev[idx];
                Hn[idx] = f2bf((1.f - zg) * ng + zg * h);
            }
        }
    }
}

// ---------------------------------------------------------------------------
// fc1: O = dropout(relu(Hn@fc1_w^T + b)). 128x64 tile bf16 MFMA.
// ---------------------------------------------------------------------------
__global__ __launch_bounds__(256) void fc1_k(
    const u16* __restrict__ Hn, const u16* __restrict__ Wb,
    const float* __restrict__ bias, const float* __restrict__ u2,
    const float* __restrict__ pl2, float* __restrict__ O) {
    __shared__ u16 sA[4096], sB[2048];
    floatx4 acc[4][2];
    #pragma unroll
    for (int i = 0; i < 4; ++i) { acc[i][0] = (floatx4){0.f,0.f,0.f,0.f}; acc[i][1] = (floatx4){0.f,0.f,0.f,0.f}; }
    const int tid = threadIdx.x;
    const int wave = tid >> 6, lane = tid & 63;
    const int m_base = blockIdx.y * 128, nb = blockIdx.x * 64;
    const int r = tid >> 2, c = tid & 3;
    const int swe = (c ^ ((r >> 1) & 3)) << 3;
    const u16* Ag = Hn + (size_t)(m_base + r) * H_DIM + swe;
    const u16* Bg = Wb + (size_t)(nb + r) * H_DIM + swe;   // r in [0,64): full B tile in 1 inst
    u16* sA0 = sA + wave * 512;
    u16* sB0 = sB + wave * 512;
    const int frow = lane & 15, fch = lane >> 4;
    const int wrow0 = (wave >> 1) * 64, wcol0 = (wave & 1) * 32;
    int aoff[4], boff[2];
    #pragma unroll
    for (int mi = 0; mi < 4; ++mi) {
        int row = wrow0 + mi * 16 + frow;
        aoff[mi] = row * 32 + ((fch ^ ((row >> 1) & 3)) << 3);
    }
    #pragma unroll
    for (int ni = 0; ni < 2; ++ni) {
        int row = wcol0 + ni * 16 + frow;
        boff[ni] = row * 32 + ((fch ^ ((row >> 1) & 3)) << 3);
    }
    for (int kk = 0; kk < 100; ++kk) {
        __syncthreads();
        gld_lds16(Ag + kk * 32, sA0);
        gld_lds16(Ag + kk * 32 + (size_t)64 * H_DIM, sA0 + 2048);
        gld_lds16(Bg + kk * 32, sB0);
        __syncthreads();
        short8 af[4], bfr[2];
        #pragma unroll
        for (int mi = 0; mi < 4; ++mi) af[mi] = *(const short8*)(sA + aoff[mi]);
        #pragma unroll
        for (int ni = 0; ni < 2; ++ni) bfr[ni] = *(const short8*)(sB + boff[ni]);
        #pragma unroll
        for (int mi = 0; mi < 4; ++mi)
            #pragma unroll
            for (int ni = 0; ni < 2; ++ni)
                acc[mi][ni] = __builtin_amdgcn_mfma_f32_16x16x32_bf16(af[mi], bfr[ni], acc[mi][ni], 0, 0, 0);
    }
    float p = sigmoidf_(pl2[0]);
    float lp = logf(p) - log1pf(-p);
    float inv = 1.0f / (1.0f - p);
    const int quad = lane >> 4, cc = lane & 15;
    #pragma unroll
    for (int ni = 0; ni < 2; ++ni) {
        int col = nb + wcol0 + ni * 16 + cc;
        float bcol = bias[col];
        #pragma unroll
        for (int mi = 0; mi < 4; ++mi) {
            int rw = m_base + wrow0 + mi * 16 + quad * 4;
            #pragma unroll
            for (int j = 0; j < 4; ++j) {
                size_t idx = (size_t)(rw + j) * OUT1 + col;
                float v = fmaxf(acc[mi][ni][j] + bcol, 0.f);
                float u = u2[idx];
                float z = sigmoidf_((lp + logf(u) - log1pf(-u)) * TEMP_INV);
                O[idx] = v * (1.0f - z) * inv;
            }
        }
    }
}

// ---------------------------------------------------------------------------
// fp32 -> bf16 conversion, 8 elts/thread
// ---------------------------------------------------------------------------
__global__ void cvt_bf16_k(const float* __restrict__ src, u16* __restrict__ dst, int n8) {
    int i = blockIdx.x * 256 + threadIdx.x;
    if (i >= n8) return;
    float4 v0 = *((const float4*)src + 2 * (size_t)i);
    float4 v1 = *((const float4*)src + 2 * (size_t)i + 1);
    short8 o;
    o[0] = (short)f2bf(v0.x); o[1] = (short)f2bf(v0.y);
    o[2] = (short)f2bf(v0.z); o[3] = (short)f2bf(v0.w);
    o[4] = (short)f2bf(v1.x); o[5] = (short)f2bf(v1.y);
    o[6] = (short)f2bf(v1.z); o[7] = (short)f2bf(v1.w);
    *(short8*)(dst + 8 * (size_t)i) = o;
}

// ---------------------------------------------------------------------------
// prep: system model + input concat (unchanged fp32)
// ---------------------------------------------------------------------------
__global__ void prep_k(const float* __restrict__ y_t, const float* __restrict__ xfp,
                       const float* __restrict__ xfpp, const float* __restrict__ yprev,
                       const float* __restrict__ dxp, const float* __restrict__ Fm,
                       const float* __restrict__ Hm,
                       float* __restrict__ xpred, float* __restrict__ resid,
                       float* __restrict__ inp) {
    int b = threadIdx.x;
    float xrow[SD], xp[SD];
    for (int k = 0; k < SD; ++k) xrow[k] = xfp[b * SD + k];
    for (int s = 0; s < SD; ++s) {
        float acc = 0.f;
        for (int k = 0; k < SD; ++k) acc += xrow[k] * Fm[s * SD + k];
        xp[s] = tanhf(acc);
        xpred[b * SD + s] = xp[s];
    }
    float res[OD];
    for (int o = 0; o < OD; ++o) {
        float acc = 0.f;
        for (int s = 0; s < SD; ++s) acc += xp[s] * Hm[o * SD + s];
        res[o] = y_t[b * OD + o] - acc;
        resid[b * OD + o] = res[o];
    }
    float* ir = inp + b * IN_DIM;
    for (int k = 0; k < SD; ++k) ir[k] = dxp[b * SD + k];
    for (int o = 0; o < OD; ++o) ir[SD + o] = res[o];
    for (int k = 0; k < SD; ++k) ir[SD + OD + k] = xrow[k] - xfpp[b * SD + k];
    for (int o = 0; o < OD; ++o) ir[SD + OD + SD + o] = yprev[b * OD + o];
}

__global__ void fc_in_k(const float* __restrict__ inp, const float* __restrict__ w,
                        const float* __restrict__ bias, float* __restrict__ a) {
    int b = blockIdx.x;
    __shared__ float row[IN_DIM];
    int t = threadIdx.x;
    if (t < IN_DIM) row[t] = inp[b * IN_DIM + t];
    __syncthreads();
    for (int j = t; j < H_DIM; j += 256) {
        float s = bias[j];
        const float* wr = w + j * IN_DIM;
        #pragma unroll 8
        for (int k = 0; k < IN_DIM; ++k) s += row[k] * wr[k];
        a[b * H_DIM + j] = fmaxf(s, 0.f);
    }
}

// X (bf16) = concrete_dropout(a, u1, p1)
__global__ void dropx_k(const float* __restrict__ a, const float* __restrict__ u1,
                        const float* __restrict__ pl1, u16* __restrict__ X) {
    int idx_in = blockIdx.x * 256 + threadIdx.x;
    int i = blockIdx.y;
    float p = sigmoidf_(pl1[0]);
    float lp = logf(p) - log1pf(-p);
    float inv = 1.0f / (1.0f - p);
    size_t gidx = (size_t)i * (B_DIM * H_DIM) + idx_in;
    float u = u1[gidx];
    float z = sigmoidf_((lp + logf(u) - log1pf(-u)) * TEMP_INV);
    X[gidx] = f2bf(a[idx_in] * (1.0f - z) * inv);
}

// K = o @ fc2_w^T + b; xf = x_pred + K @ residual
__global__ void fc2_corr_k(const float* __restrict__ O, const float* __restrict__ w,
                           const float* __restrict__ bias, const float* __restrict__ resid,
                           const float* __restrict__ xpred, float* __restrict__ xf_ens) {
    int row = blockIdx.x;
    int b = row & (B_DIM - 1);
    __shared__ __align__(16) float orow[OUT1];
    int t = threadIdx.x;
    for (int k = t; k < OUT1; k += 128) orow[k] = O[(size_t)row * OUT1 + k];
    __syncthreads();
    int s = t >> 3, oo = t & 7;
    const float* wr = w + (s * OD + oo) * OUT1;
    float sum = 0.f;
    for (int k = 0; k < OUT1; k += 4) {
        float4 ov = *(const float4*)&orow[k];
        float4 wv = *(const float4*)&wr[k];
        sum += ov.x * wv.x + ov.y * wv.y + ov.z * wv.z + ov.w * wv.w;
    }
    sum += bias[s * OD + oo];
    float v = sum * resid[b * OD + oo];
    v += __shfl_down(v, 4, 8);
    v += __shfl_down(v, 2, 8);
    v += __shfl_down(v, 1, 8);
    if (oo == 0) xf_ens[row * SD + s] = xpred[b * SD + s] + v;
}

__global__ void stats_k(const float* __restrict__ xf_ens, float* __restrict__ out) {
    int b = blockIdx.x;
    __shared__ float xf[S_ENS][SD];
    __shared__ float mean[SD];
    int t = threadIdx.x;
    if (t < S_ENS * SD) {
        int s = t >> 4, k = t & 15;
        xf[s][k] = xf_ens[s * (B_DIM * SD) + b * SD + k];
    }
    __syncthreads();
    if (t < SD) {
        float m = 0.f;
        for (int s = 0; s < S_ENS; ++s) m += xf[s][t];
        m *= (1.0f / S_ENS);
        mean[t] = m;
        out[b * SD + t] = m;
    }
    __syncthreads();
    int i = t >> 4, j = t & 15;
    float p = 0.f;
    for (int s = 0; s < S_ENS; ++s) p += (xf[s][i] - mean[i]) * (xf[s][j] - mean[j]);
    out[B_DIM * SD + b * 256 + t] = p * (1.0f / S_ENS);
}

__global__ void sumsq_k(const float* __restrict__ w, int n, float* __restrict__ accum) {
    float s = 0.f;
    for (int i = blockIdx.x * blockDim.x + threadIdx.x; i < n; i += gridDim.x * blockDim.x) {
        float v = w[i];
        s += v * v;
    }
    #pragma unroll
    for (int d = 32; d >= 1; d >>= 1) s += __shfl_down(s, d, 64);
    __shared__ float red[4];
    int lane = threadIdx.x & 63, wv = threadIdx.x >> 6;
    if (lane == 0) red[wv] = s;
    __syncthreads();
    if (threadIdx.x == 0) atomicAdd(accum, red[0] + red[1] + red[2] + red[3]);
}

__global__ void write_reg_k(const float* __restrict__ sums, const float* __restrict__ pl1,
                            const float* __restrict__ pl2, float* __restrict__ out) {
    int t = threadIdx.x;
    float p1 = sigmoidf_(pl1[0]);
    float p2 = sigmoidf_(pl2[0]);
    float ent1 = p1 * logf(p1) + (1.f - p1) * log1pf(-p1);
    float ent2 = p2 * logf(p2) + (1.f - p2) * log1pf(-p2);
    float reg = sums[0] / (1.f - p1) + (float)H_DIM * ent1
              + sums[1] / (1.f - p2) + (float)OUT1 * ent2;
    if (t < S_ENS) out[B_DIM * SD + B_DIM * SD * SD + t] = reg;
}

// ---------------------------------------------------------------------------
extern "C" void kernel_launch(void* const* d_in, const int* in_sizes, int n_in,
                              void* d_out, int out_size, void* d_ws, size_t ws_size,
                              hipStream_t stream) {
    const float* y_t     = (const float*)d_in[0];
    const float* xfp     = (const float*)d_in[1];
    const float* xfpp    = (const float*)d_in[2];
    const float* yprev   = (const float*)d_in[3];
    const float* dxp     = (const float*)d_in[4];
    const float* hprev   = (const float*)d_in[5];
    const float* Fm      = (const float*)d_in[6];
    const float* Hm      = (const float*)d_in[7];
    const float* fc_in_w = (const float*)d_in[8];
    const float* fc_in_b = (const float*)d_in[9];
    const float* W_ih    = (const float*)d_in[10];
    const float* W_hh    = (const float*)d_in[11];
    const float* b_ih    = (const float*)d_in[12];
    const float* b_hh    = (const float*)d_in[13];
    const float* fc1_w   = (const float*)d_in[14];
    const float* fc1_b   = (const float*)d_in[15];
    const float* fc2_w   = (const float*)d_in[16];
    const float* fc2_b   = (const float*)d_in[17];
    const float* pl1     = (const float*)d_in[18];
    const float* pl2     = (const float*)d_in[19];
    const float* u1      = (const float*)d_in[20];
    const float* u2      = (const float*)d_in[21];
    float* out = (float*)d_out;
    char* ws = (char*)d_ws;

    // byte offsets (all 256-aligned by construction)
    const size_t SZ_W    = (size_t)3 * H_DIM * H_DIM * 2;   // 61,440,000 B
    const size_t SZ_MH   = (size_t)M_ROWS * H_DIM * 2;      // 16,384,000 B
    size_t off = 0;
    u16* Wihbf  = (u16*)(ws + off); off += SZ_W;
    u16* Whhbf  = (u16*)(ws + off); off += SZ_W;
    u16* Rb     = (u16*)(ws + off); off += SZ_MH;
    u16* Zb     = (u16*)(ws + off); off += SZ_MH;
    u16* Gb     = (u16*)(ws + off); off += SZ_MH;
    u16* Xbf    = (u16*)(ws + off); off += SZ_MH;
    u16* Hpbf   = (u16*)(ws + off); off += SZ_MH;           // phase-A A-operand
    u16* Hnbf   = Hpbf;                                     // alias: Hpbf dead before phase-B writes Hn
    u16* fc1wbf = (u16*)(ws + off); off += (size_t)OUT1 * H_DIM * 2;
    float* O_buf   = (float*)(ws + off); off += (size_t)M_ROWS * OUT1 * 4;
    float* a_buf   = (float*)(ws + off); off += (size_t)B_DIM * H_DIM * 4;
    float* xf_buf  = (float*)(ws + off); off += (size_t)M_ROWS * SD * 4;
    float* xpred_b = (float*)(ws + off); off += (size_t)B_DIM * SD * 4;
    float* res_b   = (float*)(ws + off); off += (size_t)B_DIM * OD * 4;
    float* inp_b   = (float*)(ws + off); off += (size_t)B_DIM * IN_DIM * 4;
    float* sums_b  = (float*)(ws + off); off += 256;

    hipMemsetAsync(sums_b, 0, 2 * sizeof(float), stream);

    // small fp32 front-end
    prep_k<<<1, 256, 0, stream>>>(y_t, xfp, xfpp, yprev, dxp, Fm, Hm, xpred_b, res_b, inp_b);
    fc_in_k<<<B_DIM, 256, 0, stream>>>(inp_b, fc_in_w, fc_in_b, a_buf);
    dropx_k<<<dim3(B_DIM * H_DIM / 256, S_ENS), 256, 0, stream>>>(a_buf, u1, pl1, Xbf);

    // bf16 conversions
    cvt_bf16_k<<<15000, 256, 0, stream>>>(W_ih, Wihbf, 3 * H_DIM * H_DIM / 8);
    cvt_bf16_k<<<15000, 256, 0, stream>>>(W_hh, Whhbf, 3 * H_DIM * H_DIM / 8);
    cvt_bf16_k<<<4000, 256, 0, stream>>>(hprev, Hpbf, M_ROWS * H_DIM / 8);
    cvt_bf16_k<<<800, 256, 0, stream>>>(fc1_w, fc1wbf, OUT1 * H_DIM / 8);

    // GRU: phase A (raw r/z gate sums + gh_n), phase B (gx_n + fused epilogue)
    gru_gemm_a<<<dim3(H_DIM / 128, M_ROWS / 128, 3), 256, 0, stream>>>(
        Xbf, Hpbf, Wihbf, Whhbf, Rb, Zb, Gb);
    gru_gemm_b<<<dim3(H_DIM / 128, M_ROWS / 128), 256, 0, stream>>>(
        Xbf, Wihbf, Rb, Zb, Gb, b_ih, b_hh, hprev, Hnbf);

    // fc1 + dropout
    fc1_k<<<dim3(OUT1 / 64, M_ROWS / 128), 256, 0, stream>>>(Hnbf, fc1wbf, fc1_b, u2, pl2, O_buf);

    // tail
    fc2_corr_k<<<M_ROWS, 128, 0, stream>>>(O_buf, fc2_w, fc2_b, res_b, xpred_b, xf_buf);
    stats_k<<<B_DIM, 256, 0, stream>>>(xf_buf, out);
    sumsq_k<<<256, 256, 0, stream>>>(fc_in_w, H_DIM * IN_DIM, sums_b);
    sumsq_k<<<1024, 256, 0, stream>>>(fc1_w, OUT1 * H_DIM, sums_b + 1);
    write_reg_k<<<1, 64, 0, stream>>>(sums_b, pl1, pl2, out);
}

// Round 3
// 1007.598 us; speedup vs baseline: 5.6552x; 1.1734x over previous
//
#include <hip/hip_runtime.h>
#include <hip/hip_bf16.h>
#include <math.h>

// Problem constants
#define S_ENS 10
#define B_DIM 256
#define SD 16
#define OD 8
#define H_DIM 3200
#define OUT1 512
#define IN_DIM 48
#define M_ROWS (S_ENS * B_DIM)     // 2560
#define TEMP_INV 10.0f

typedef unsigned short u16;
typedef __attribute__((ext_vector_type(8))) short short8;
typedef __attribute__((ext_vector_type(4))) short short4v;   // 8B packed bf16x4
typedef __attribute__((ext_vector_type(4))) float floatx4;

__device__ __forceinline__ float sigmoidf_(float x) { return 1.0f / (1.0f + __expf(-x)); }
__device__ __forceinline__ float fast_tanh(float x) {
    x = fminf(fmaxf(x, -15.f), 15.f);
    float e = __expf(2.f * x);
    return (e - 1.f) / (e + 1.f);
}

// fp32 -> bf16 round-to-nearest-even
__device__ __forceinline__ u16 f2bf(float f) {
    union { float f; unsigned u; } v; v.f = f;
    unsigned u = v.u + 0x7fffu + ((v.u >> 16) & 1u);
    return (u16)(u >> 16);
}
__device__ __forceinline__ float bf2f(u16 h) {
    union { unsigned u; float f; } v; v.u = ((unsigned)h) << 16;
    return v.f;
}

// async global->LDS, 16B per lane. LDS dest: wave-uniform base + lane*16.
__device__ __forceinline__ void gld_lds16(const u16* g, u16* l) {
    __builtin_amdgcn_global_load_lds((const __attribute__((address_space(1))) void*)g,
                                     (__attribute__((address_space(3))) void*)l, 16, 0, 0);
}

// ---------------------------------------------------------------------------
// 128x128-tile bf16 MFMA K-loop (BK=32), XOR-swizzled LDS (conflict-free,
// verified round 2: SQ_LDS_BANK_CONFLICT == 0).
// ---------------------------------------------------------------------------
__device__ __forceinline__ void kloop128(const u16* __restrict__ A, const u16* __restrict__ B,
                                         int m_base, int n_base, int kiters,
                                         u16* sA, u16* sB, floatx4 (&acc)[4][4]) {
    const int tid = threadIdx.x;
    const int wave = tid >> 6, lane = tid & 63;
    const int r = tid >> 2, c = tid & 3;
    const int swe = (c ^ ((r >> 1) & 3)) << 3;
    const u16* Ag = A + (size_t)(m_base + r) * H_DIM + swe;
    const u16* Bg = B + (size_t)(n_base + r) * H_DIM + swe;
    u16* sA0 = sA + wave * 512;
    u16* sB0 = sB + wave * 512;
    const int frow = lane & 15, fch = lane >> 4;
    const int wrow0 = (wave >> 1) * 64, wcol0 = (wave & 1) * 64;
    int aoff[4], boff[4];
    #pragma unroll
    for (int mi = 0; mi < 4; ++mi) {
        int row = wrow0 + mi * 16 + frow;
        aoff[mi] = row * 32 + ((fch ^ ((row >> 1) & 3)) << 3);
    }
    #pragma unroll
    for (int ni = 0; ni < 4; ++ni) {
        int row = wcol0 + ni * 16 + frow;
        boff[ni] = row * 32 + ((fch ^ ((row >> 1) & 3)) << 3);
    }
    for (int kk = 0; kk < kiters; ++kk) {
        const u16* ga = Ag + kk * 32;
        const u16* gb = Bg + kk * 32;
        __syncthreads();
        gld_lds16(ga, sA0);
        gld_lds16(ga + (size_t)64 * H_DIM, sA0 + 2048);
        gld_lds16(gb, sB0);
        gld_lds16(gb + (size_t)64 * H_DIM, sB0 + 2048);
        __syncthreads();
        short8 af[4], bfr[4];
        #pragma unroll
        for (int mi = 0; mi < 4; ++mi) af[mi] = *(const short8*)(sA + aoff[mi]);
        #pragma unroll
        for (int ni = 0; ni < 4; ++ni) bfr[ni] = *(const short8*)(sB + boff[ni]);
        #pragma unroll
        for (int mi = 0; mi < 4; ++mi)
            #pragma unroll
            for (int ni = 0; ni < 4; ++ni)
                acc[mi][ni] = __builtin_amdgcn_mfma_f32_16x16x32_bf16(af[mi], bfr[ni], acc[mi][ni], 0, 0, 0);
    }
}

// ---------------------------------------------------------------------------
// Phase A. grid = (M-tiles=20, N-tiles=25, 3); x fastest => concurrent blocks
// share the same W-tile (L2/L3 reuse of the 123 MB of weights).
// z=0: r = sigmoid(X@Wih_r^T + Hp@Whh_r^T + bir + bhr)   (activated!)
// z=1: z likewise; z=2: ghn' = Hp@Whh_n^T + bhn          (raw + bias)
// Output in PACKED fragment-major layout: tile(nbi*20+bmi) * 16384
//   + wave*4096 + (mi*4+ni)*256 + lane*4 + j   -> coalesced 8B stores.
// ---------------------------------------------------------------------------
__global__ __launch_bounds__(256) void gru_gemm_a(
    const u16* __restrict__ Xbf, const u16* __restrict__ Hpbf,
    const u16* __restrict__ Wih, const u16* __restrict__ Whh,
    const float* __restrict__ b_ih, const float* __restrict__ b_hh,
    u16* __restrict__ Rb, u16* __restrict__ Zb, u16* __restrict__ Gb) {
    __shared__ u16 sA[4096], sB[4096];
    floatx4 acc[4][4];
    #pragma unroll
    for (int i = 0; i < 4; ++i)
        #pragma unroll
        for (int j = 0; j < 4; ++j) acc[i][j] = (floatx4){0.f, 0.f, 0.f, 0.f};
    const int g = blockIdx.z;
    const int bmi = blockIdx.x, nbi = blockIdx.y;
    const int m_base = bmi * 128, nb = nbi * 128;
    const size_t gstride = (size_t)H_DIM * H_DIM;
    u16* outp;
    if (g == 0) {
        kloop128(Xbf, Wih, m_base, nb, 100, sA, sB, acc);
        kloop128(Hpbf, Whh, m_base, nb, 100, sA, sB, acc);
        outp = Rb;
    } else if (g == 1) {
        kloop128(Xbf, Wih + gstride, m_base, nb, 100, sA, sB, acc);
        kloop128(Hpbf, Whh + gstride, m_base, nb, 100, sA, sB, acc);
        outp = Zb;
    } else {
        kloop128(Hpbf, Whh + 2 * gstride, m_base, nb, 100, sA, sB, acc);
        outp = Gb;
    }
    const int lane = threadIdx.x & 63, wave = threadIdx.x >> 6;
    const int wcol0 = (wave & 1) * 64, cc = lane & 15;
    const size_t tbase = (size_t)(nbi * 20 + bmi) * 16384 + wave * 4096 + lane * 4;
    #pragma unroll
    for (int ni = 0; ni < 4; ++ni) {
        int col = nb + wcol0 + ni * 16 + cc;
        float bsum;
        if (g == 0)      bsum = b_ih[col] + b_hh[col];
        else if (g == 1) bsum = b_ih[H_DIM + col] + b_hh[H_DIM + col];
        else             bsum = b_hh[2 * H_DIM + col];
        #pragma unroll
        for (int mi = 0; mi < 4; ++mi) {
            short4v o;
            #pragma unroll
            for (int j = 0; j < 4; ++j) {
                float v = acc[mi][ni][j] + bsum;
                if (g < 2) v = sigmoidf_(v);
                o[j] = (short)f2bf(v);
            }
            *(short4v*)(outp + tbase + (mi * 4 + ni) * 256) = o;
        }
    }
}

// ---------------------------------------------------------------------------
// Phase B: gx_n GEMM + GRU combine. Reads packed r/z/ghn' (8B coalesced),
// fast tanh, writes Hn row-major bf16.
// ---------------------------------------------------------------------------
__global__ __launch_bounds__(256) void gru_gemm_b(
    const u16* __restrict__ Xbf, const u16* __restrict__ Wih,
    const u16* __restrict__ Rb, const u16* __restrict__ Zb, const u16* __restrict__ Gb,
    const float* __restrict__ b_ih,
    const float* __restrict__ hprev, u16* __restrict__ Hn) {
    __shared__ u16 sA[4096], sB[4096];
    floatx4 acc[4][4];
    #pragma unroll
    for (int i = 0; i < 4; ++i)
        #pragma unroll
        for (int j = 0; j < 4; ++j) acc[i][j] = (floatx4){0.f, 0.f, 0.f, 0.f};
    const int bmi = blockIdx.x, nbi = blockIdx.y;
    const int m_base = bmi * 128, nb = nbi * 128;
    kloop128(Xbf, Wih + (size_t)2 * H_DIM * H_DIM, m_base, nb, 100, sA, sB, acc);
    const int lane = threadIdx.x & 63, wave = threadIdx.x >> 6;
    const int wrow0 = (wave >> 1) * 64, wcol0 = (wave & 1) * 64;
    const int quad = lane >> 4, cc = lane & 15;
    const size_t tbase = (size_t)(nbi * 20 + bmi) * 16384 + wave * 4096 + lane * 4;
    #pragma unroll
    for (int ni = 0; ni < 4; ++ni) {
        int col = nb + wcol0 + ni * 16 + cc;
        float bin_ = b_ih[2 * H_DIM + col];
        #pragma unroll
        for (int mi = 0; mi < 4; ++mi) {
            size_t pidx = tbase + (mi * 4 + ni) * 256;
            short4v rv = *(const short4v*)(Rb + pidx);
            short4v zv = *(const short4v*)(Zb + pidx);
            short4v gv = *(const short4v*)(Gb + pidx);
            int rw = m_base + wrow0 + mi * 16 + quad * 4;
            #pragma unroll
            for (int j = 0; j < 4; ++j) {
                float r = bf2f((u16)rv[j]);
                float z = bf2f((u16)zv[j]);
                float gh = bf2f((u16)gv[j]);
                float n = fast_tanh(acc[mi][ni][j] + bin_ + r * gh);
                size_t idx = (size_t)(rw + j) * H_DIM + col;
                float h = hprev[idx];
                Hn[idx] = f2bf((1.f - z) * n + z * h);
            }
        }
    }
}

// ---------------------------------------------------------------------------
// fc1: O = dropout(relu(Hn@fc1_w^T + b)). 128x64 tile bf16 MFMA.
// ---------------------------------------------------------------------------
__global__ __launch_bounds__(256) void fc1_k(
    const u16* __restrict__ Hn, const u16* __restrict__ Wb,
    const float* __restrict__ bias, const float* __restrict__ u2,
    const float* __restrict__ pl2, float* __restrict__ O) {
    __shared__ u16 sA[4096], sB[2048];
    floatx4 acc[4][2];
    #pragma unroll
    for (int i = 0; i < 4; ++i) { acc[i][0] = (floatx4){0.f,0.f,0.f,0.f}; acc[i][1] = (floatx4){0.f,0.f,0.f,0.f}; }
    const int tid = threadIdx.x;
    const int wave = tid >> 6, lane = tid & 63;
    const int m_base = blockIdx.y * 128, nb = blockIdx.x * 64;
    const int r = tid >> 2, c = tid & 3;
    const int swe = (c ^ ((r >> 1) & 3)) << 3;
    const u16* Ag = Hn + (size_t)(m_base + r) * H_DIM + swe;
    const u16* Bg = Wb + (size_t)(nb + r) * H_DIM + swe;
    u16* sA0 = sA + wave * 512;
    u16* sB0 = sB + wave * 512;
    const int frow = lane & 15, fch = lane >> 4;
    const int wrow0 = (wave >> 1) * 64, wcol0 = (wave & 1) * 32;
    int aoff[4], boff[2];
    #pragma unroll
    for (int mi = 0; mi < 4; ++mi) {
        int row = wrow0 + mi * 16 + frow;
        aoff[mi] = row * 32 + ((fch ^ ((row >> 1) & 3)) << 3);
    }
    #pragma unroll
    for (int ni = 0; ni < 2; ++ni) {
        int row = wcol0 + ni * 16 + frow;
        boff[ni] = row * 32 + ((fch ^ ((row >> 1) & 3)) << 3);
    }
    for (int kk = 0; kk < 100; ++kk) {
        __syncthreads();
        gld_lds16(Ag + kk * 32, sA0);
        gld_lds16(Ag + kk * 32 + (size_t)64 * H_DIM, sA0 + 2048);
        gld_lds16(Bg + kk * 32, sB0);
        __syncthreads();
        short8 af[4], bfr[2];
        #pragma unroll
        for (int mi = 0; mi < 4; ++mi) af[mi] = *(const short8*)(sA + aoff[mi]);
        #pragma unroll
        for (int ni = 0; ni < 2; ++ni) bfr[ni] = *(const short8*)(sB + boff[ni]);
        #pragma unroll
        for (int mi = 0; mi < 4; ++mi)
            #pragma unroll
            for (int ni = 0; ni < 2; ++ni)
                acc[mi][ni] = __builtin_amdgcn_mfma_f32_16x16x32_bf16(af[mi], bfr[ni], acc[mi][ni], 0, 0, 0);
    }
    float p = sigmoidf_(pl2[0]);
    float lp = __logf(p) - log1pf(-p);
    float inv = 1.0f / (1.0f - p);
    const int quad = lane >> 4, cc = lane & 15;
    #pragma unroll
    for (int ni = 0; ni < 2; ++ni) {
        int col = nb + wcol0 + ni * 16 + cc;
        float bcol = bias[col];
        #pragma unroll
        for (int mi = 0; mi < 4; ++mi) {
            int rw = m_base + wrow0 + mi * 16 + quad * 4;
            #pragma unroll
            for (int j = 0; j < 4; ++j) {
                size_t idx = (size_t)(rw + j) * OUT1 + col;
                float v = fmaxf(acc[mi][ni][j] + bcol, 0.f);
                float u = u2[idx];
                float z = sigmoidf_((lp + __logf(u) - log1pf(-u)) * TEMP_INV);
                O[idx] = v * (1.0f - z) * inv;
            }
        }
    }
}

// ---------------------------------------------------------------------------
// fp32 -> bf16 conversion, 8 elts/thread
// ---------------------------------------------------------------------------
__global__ void cvt_bf16_k(const float* __restrict__ src, u16* __restrict__ dst, int n8) {
    int i = blockIdx.x * 256 + threadIdx.x;
    if (i >= n8) return;
    float4 v0 = *((const float4*)src + 2 * (size_t)i);
    float4 v1 = *((const float4*)src + 2 * (size_t)i + 1);
    short8 o;
    o[0] = (short)f2bf(v0.x); o[1] = (short)f2bf(v0.y);
    o[2] = (short)f2bf(v0.z); o[3] = (short)f2bf(v0.w);
    o[4] = (short)f2bf(v1.x); o[5] = (short)f2bf(v1.y);
    o[6] = (short)f2bf(v1.z); o[7] = (short)f2bf(v1.w);
    *(short8*)(dst + 8 * (size_t)i) = o;
}

// ---------------------------------------------------------------------------
// prep: system model + input concat (fp32, exact)
// ---------------------------------------------------------------------------
__global__ void prep_k(const float* __restrict__ y_t, const float* __restrict__ xfp,
                       const float* __restrict__ xfpp, const float* __restrict__ yprev,
                       const float* __restrict__ dxp, const float* __restrict__ Fm,
                       const float* __restrict__ Hm,
                       float* __restrict__ xpred, float* __restrict__ resid,
                       float* __restrict__ inp) {
    int b = threadIdx.x;
    float xrow[SD], xp[SD];
    for (int k = 0; k < SD; ++k) xrow[k] = xfp[b * SD + k];
    for (int s = 0; s < SD; ++s) {
        float acc = 0.f;
        for (int k = 0; k < SD; ++k) acc += xrow[k] * Fm[s * SD + k];
        xp[s] = tanhf(acc);
        xpred[b * SD + s] = xp[s];
    }
    float res[OD];
    for (int o = 0; o < OD; ++o) {
        float acc = 0.f;
        for (int s = 0; s < SD; ++s) acc += xp[s] * Hm[o * SD + s];
        res[o] = y_t[b * OD + o] - acc;
        resid[b * OD + o] = res[o];
    }
    float* ir = inp + b * IN_DIM;
    for (int k = 0; k < SD; ++k) ir[k] = dxp[b * SD + k];
    for (int o = 0; o < OD; ++o) ir[SD + o] = res[o];
    for (int k = 0; k < SD; ++k) ir[SD + OD + k] = xrow[k] - xfpp[b * SD + k];
    for (int o = 0; o < OD; ++o) ir[SD + OD + SD + o] = yprev[b * OD + o];
}

__global__ void fc_in_k(const float* __restrict__ inp, const float* __restrict__ w,
                        const float* __restrict__ bias, float* __restrict__ a) {
    int b = blockIdx.x;
    __shared__ float row[IN_DIM];
    int t = threadIdx.x;
    if (t < IN_DIM) row[t] = inp[b * IN_DIM + t];
    __syncthreads();
    for (int j = t; j < H_DIM; j += 256) {
        float s = bias[j];
        const float* wr = w + j * IN_DIM;
        #pragma unroll 8
        for (int k = 0; k < IN_DIM; ++k) s += row[k] * wr[k];
        a[b * H_DIM + j] = fmaxf(s, 0.f);
    }
}

// X (bf16) = concrete_dropout(a, u1, p1)
__global__ void dropx_k(const float* __restrict__ a, const float* __restrict__ u1,
                        const float* __restrict__ pl1, u16* __restrict__ X) {
    int idx_in = blockIdx.x * 256 + threadIdx.x;
    int i = blockIdx.y;
    float p = sigmoidf_(pl1[0]);
    float lp = __logf(p) - log1pf(-p);
    float inv = 1.0f / (1.0f - p);
    size_t gidx = (size_t)i * (B_DIM * H_DIM) + idx_in;
    float u = u1[gidx];
    float z = sigmoidf_((lp + __logf(u) - log1pf(-u)) * TEMP_INV);
    X[gidx] = f2bf(a[idx_in] * (1.0f - z) * inv);
}

// K = o @ fc2_w^T + b; xf = x_pred + K @ residual
__global__ void fc2_corr_k(const float* __restrict__ O, const float* __restrict__ w,
                           const float* __restrict__ bias, const float* __restrict__ resid,
                           const float* __restrict__ xpred, float* __restrict__ xf_ens) {
    int row = blockIdx.x;
    int b = row & (B_DIM - 1);
    __shared__ __align__(16) float orow[OUT1];
    int t = threadIdx.x;
    for (int k = t; k < OUT1; k += 128) orow[k] = O[(size_t)row * OUT1 + k];
    __syncthreads();
    int s = t >> 3, oo = t & 7;
    const float* wr = w + (s * OD + oo) * OUT1;
    float sum = 0.f;
    for (int k = 0; k < OUT1; k += 4) {
        float4 ov = *(const float4*)&orow[k];
        float4 wv = *(const float4*)&wr[k];
        sum += ov.x * wv.x + ov.y * wv.y + ov.z * wv.z + ov.w * wv.w;
    }
    sum += bias[s * OD + oo];
    float v = sum * resid[b * OD + oo];
    v += __shfl_down(v, 4, 8);
    v += __shfl_down(v, 2, 8);
    v += __shfl_down(v, 1, 8);
    if (oo == 0) xf_ens[row * SD + s] = xpred[b * SD + s] + v;
}

__global__ void stats_k(const float* __restrict__ xf_ens, float* __restrict__ out) {
    int b = blockIdx.x;
    __shared__ float xf[S_ENS][SD];
    __shared__ float mean[SD];
    int t = threadIdx.x;
    if (t < S_ENS * SD) {
        int s = t >> 4, k = t & 15;
        xf[s][k] = xf_ens[s * (B_DIM * SD) + b * SD + k];
    }
    __syncthreads();
    if (t < SD) {
        float m = 0.f;
        for (int s = 0; s < S_ENS; ++s) m += xf[s][t];
        m *= (1.0f / S_ENS);
        mean[t] = m;
        out[b * SD + t] = m;
    }
    __syncthreads();
    int i = t >> 4, j = t & 15;
    float p = 0.f;
    for (int s = 0; s < S_ENS; ++s) p += (xf[s][i] - mean[i]) * (xf[s][j] - mean[j]);
    out[B_DIM * SD + b * 256 + t] = p * (1.0f / S_ENS);
}

__global__ void sumsq_k(const float* __restrict__ w, int n, float* __restrict__ accum) {
    float s = 0.f;
    for (int i = blockIdx.x * blockDim.x + threadIdx.x; i < n; i += gridDim.x * blockDim.x) {
        float v = w[i];
        s += v * v;
    }
    #pragma unroll
    for (int d = 32; d >= 1; d >>= 1) s += __shfl_down(s, d, 64);
    __shared__ float red[4];
    int lane = threadIdx.x & 63, wv = threadIdx.x >> 6;
    if (lane == 0) red[wv] = s;
    __syncthreads();
    if (threadIdx.x == 0) atomicAdd(accum, red[0] + red[1] + red[2] + red[3]);
}

__global__ void write_reg_k(const float* __restrict__ sums, const float* __restrict__ pl1,
                            const float* __restrict__ pl2, float* __restrict__ out) {
    int t = threadIdx.x;
    float p1 = sigmoidf_(pl1[0]);
    float p2 = sigmoidf_(pl2[0]);
    float ent1 = p1 * logf(p1) + (1.f - p1) * log1pf(-p1);
    float ent2 = p2 * logf(p2) + (1.f - p2) * log1pf(-p2);
    float reg = sums[0] / (1.f - p1) + (float)H_DIM * ent1
              + sums[1] / (1.f - p2) + (float)OUT1 * ent2;
    if (t < S_ENS) out[B_DIM * SD + B_DIM * SD * SD + t] = reg;
}

// ---------------------------------------------------------------------------
extern "C" void kernel_launch(void* const* d_in, const int* in_sizes, int n_in,
                              void* d_out, int out_size, void* d_ws, size_t ws_size,
                              hipStream_t stream) {
    const float* y_t     = (const float*)d_in[0];
    const float* xfp     = (const float*)d_in[1];
    const float* xfpp    = (const float*)d_in[2];
    const float* yprev   = (const float*)d_in[3];
    const float* dxp     = (const float*)d_in[4];
    const float* hprev   = (const float*)d_in[5];
    const float* Fm      = (const float*)d_in[6];
    const float* Hm      = (const float*)d_in[7];
    const float* fc_in_w = (const float*)d_in[8];
    const float* fc_in_b = (const float*)d_in[9];
    const float* W_ih    = (const float*)d_in[10];
    const float* W_hh    = (const float*)d_in[11];
    const float* b_ih    = (const float*)d_in[12];
    const float* b_hh    = (const float*)d_in[13];
    const float* fc1_w   = (const float*)d_in[14];
    const float* fc1_b   = (const float*)d_in[15];
    const float* fc2_w   = (const float*)d_in[16];
    const float* fc2_b   = (const float*)d_in[17];
    const float* pl1     = (const float*)d_in[18];
    const float* pl2     = (const float*)d_in[19];
    const float* u1      = (const float*)d_in[20];
    const float* u2      = (const float*)d_in[21];
    float* out = (float*)d_out;
    char* ws = (char*)d_ws;

    const size_t SZ_W    = (size_t)3 * H_DIM * H_DIM * 2;
    const size_t SZ_MH   = (size_t)M_ROWS * H_DIM * 2;
    size_t off = 0;
    u16* Wihbf  = (u16*)(ws + off); off += SZ_W;
    u16* Whhbf  = (u16*)(ws + off); off += SZ_W;
    u16* Rb     = (u16*)(ws + off); off += SZ_MH;
    u16* Zb     = (u16*)(ws + off); off += SZ_MH;
    u16* Gb     = (u16*)(ws + off); off += SZ_MH;
    u16* Xbf    = (u16*)(ws + off); off += SZ_MH;
    u16* Hpbf   = (u16*)(ws + off); off += SZ_MH;
    u16* Hnbf   = Hpbf;                       // alias: Hpbf dead before phase-B writes
    u16* fc1wbf = (u16*)(ws + off); off += (size_t)OUT1 * H_DIM * 2;
    float* O_buf   = (float*)(ws + off); off += (size_t)M_ROWS * OUT1 * 4;
    float* a_buf   = (float*)(ws + off); off += (size_t)B_DIM * H_DIM * 4;
    float* xf_buf  = (float*)(ws + off); off += (size_t)M_ROWS * SD * 4;
    float* xpred_b = (float*)(ws + off); off += (size_t)B_DIM * SD * 4;
    float* res_b   = (float*)(ws + off); off += (size_t)B_DIM * OD * 4;
    float* inp_b   = (float*)(ws + off); off += (size_t)B_DIM * IN_DIM * 4;
    float* sums_b  = (float*)(ws + off); off += 256;

    hipMemsetAsync(sums_b, 0, 2 * sizeof(float), stream);

    prep_k<<<1, 256, 0, stream>>>(y_t, xfp, xfpp, yprev, dxp, Fm, Hm, xpred_b, res_b, inp_b);
    fc_in_k<<<B_DIM, 256, 0, stream>>>(inp_b, fc_in_w, fc_in_b, a_buf);
    dropx_k<<<dim3(B_DIM * H_DIM / 256, S_ENS), 256, 0, stream>>>(a_buf, u1, pl1, Xbf);

    cvt_bf16_k<<<15000, 256, 0, stream>>>(W_ih, Wihbf, 3 * H_DIM * H_DIM / 8);
    cvt_bf16_k<<<15000, 256, 0, stream>>>(W_hh, Whhbf, 3 * H_DIM * H_DIM / 8);
    cvt_bf16_k<<<4000, 256, 0, stream>>>(hprev, Hpbf, M_ROWS * H_DIM / 8);
    cvt_bf16_k<<<800, 256, 0, stream>>>(fc1_w, fc1wbf, OUT1 * H_DIM / 8);

    // GRU: grid x = M-tiles (fastest) so concurrent blocks share W-tiles.
    gru_gemm_a<<<dim3(M_ROWS / 128, H_DIM / 128, 3), 256, 0, stream>>>(
        Xbf, Hpbf, Wihbf, Whhbf, b_ih, b_hh, Rb, Zb, Gb);
    gru_gemm_b<<<dim3(M_ROWS / 128, H_DIM / 128), 256, 0, stream>>>(
        Xbf, Wihbf, Rb, Zb, Gb, b_ih, hprev, Hnbf);

    fc1_k<<<dim3(OUT1 / 64, M_ROWS / 128), 256, 0, stream>>>(Hnbf, fc1wbf, fc1_b, u2, pl2, O_buf);

    fc2_corr_k<<<M_ROWS, 128, 0, stream>>>(O_buf, fc2_w, fc2_b, res_b, xpred_b, xf_buf);
    stats_k<<<B_DIM, 256, 0, stream>>>(xf_buf, out);
    sumsq_k<<<256, 256, 0, stream>>>(fc_in_w, H_DIM * IN_DIM, sums_b);
    sumsq_k<<<1024, 256, 0, stream>>>(fc1_w, OUT1 * H_DIM, sums_b + 1);
    write_reg_k<<<1, 64, 0, stream>>>(sums_b, pl1, pl2, out);
}